// Round 12
// baseline (59.535 us; speedup 1.0000x reference)
//
#include <hip/hip_runtime.h>
#include <hip/hip_bf16.h>
#include <stdint.h>

#define N_ROWS 4096
#define D_DIM  256
#define TWO_N  8192
#define ROWB   512                       // bytes per bf16 row
#define C_EXP  2.8853900817779268f       // 2*log2(e): exp(2*dot)=2^(dot*2*log2e)

typedef __attribute__((ext_vector_type(8))) short short8;
typedef __attribute__((ext_vector_type(4))) float f32x4;

__device__ __forceinline__ unsigned bf16rne(float f) {
    unsigned u = __float_as_uint(f);
    return (u + 0x7fffu + ((u >> 16) & 1u)) >> 16;
}
__device__ __forceinline__ float bf16val(unsigned bits) {
    return __uint_as_float(bits << 16);
}

// ---------- K1: normalize -> bf16 reps, exact pos-pair sims, bf16 self-dot exp, zero rowsum ----------
__global__ __launch_bounds__(256) void kprep(const float* __restrict__ zi,
                                             const float* __restrict__ zj,
                                             unsigned short* __restrict__ reps,
                                             float* __restrict__ pos,
                                             float* __restrict__ selfexp,
                                             float* __restrict__ rowsum) {
    int wave = threadIdx.x >> 6, lane = threadIdx.x & 63;
    int k = blockIdx.x * 4 + wave;   // 0..4095
    float4 a = *(const float4*)(zi + (size_t)k * D_DIM + lane * 4);
    float4 b = *(const float4*)(zj + (size_t)k * D_DIM + lane * 4);
    float dii = a.x * a.x + a.y * a.y + a.z * a.z + a.w * a.w;
    float djj = b.x * b.x + b.y * b.y + b.z * b.z + b.w * b.w;
    float dij = a.x * b.x + a.y * b.y + a.z * b.z + a.w * b.w;
#pragma unroll
    for (int m = 1; m < 64; m <<= 1) {
        dii += __shfl_xor(dii, m, 64);
        djj += __shfl_xor(djj, m, 64);
        dij += __shfl_xor(dij, m, 64);
    }
    float si = 1.0f / fmaxf(sqrtf(dii), 1e-12f);
    float sj = 1.0f / fmaxf(sqrtf(djj), 1e-12f);

    unsigned a0 = bf16rne(a.x * si), a1 = bf16rne(a.y * si);
    unsigned a2 = bf16rne(a.z * si), a3 = bf16rne(a.w * si);
    unsigned b0 = bf16rne(b.x * sj), b1 = bf16rne(b.y * sj);
    unsigned b2 = bf16rne(b.z * sj), b3 = bf16rne(b.w * sj);
    {
        uint2 o; o.x = a0 | (a1 << 16); o.y = a2 | (a3 << 16);
        *(uint2*)(reps + (size_t)k * D_DIM + lane * 4) = o;
    }
    {
        uint2 o; o.x = b0 | (b1 << 16); o.y = b2 | (b3 << 16);
        *(uint2*)(reps + (size_t)(k + N_ROWS) * D_DIM + lane * 4) = o;
    }
    float fa0 = bf16val(a0), fa1 = bf16val(a1), fa2 = bf16val(a2), fa3 = bf16val(a3);
    float fb0 = bf16val(b0), fb1 = bf16val(b1), fb2 = bf16val(b2), fb3 = bf16val(b3);
    float sa = fa0 * fa0 + fa1 * fa1 + fa2 * fa2 + fa3 * fa3;
    float sb = fb0 * fb0 + fb1 * fb1 + fb2 * fb2 + fb3 * fb3;
#pragma unroll
    for (int m = 1; m < 64; m <<= 1) {
        sa += __shfl_xor(sa, m, 64);
        sb += __shfl_xor(sb, m, 64);
    }
    if (lane == 0) {
        float p = dij * si * sj * 2.0f;   // /TEMPERATURE
        pos[k] = p;
        pos[k + N_ROWS] = p;
        selfexp[k] = __builtin_amdgcn_exp2f(sa * C_EXP);
        selfexp[k + N_ROWS] = __builtin_amdgcn_exp2f(sb * C_EXP);
    }
    if (threadIdx.x < 8) rowsum[blockIdx.x * 8 + threadIdx.x] = 0.0f;
}

// ---------- K2: one 128x128 tile per block; wrap symmetry; R10-verbatim inner loop ----------
// 2080 blocks = {(rt,s): rt in 0..63, s in 0..32, s==32 only for rt<32}; ct=(rt+s)&63.
// Coverage (validated R11): each ordered pair (i,j), i!=j, exactly once — direct for
// s in 0..32; mirrors via col-emission (colsum of exp == rowsum of exp^T). s=0 tile
// emits rows only; diagonal self-term subtracted in kfinal via selfexp.
// Per block: 2 sub-tiles of 64 cols (stage/sync/mfma/sync/epi each), then ONE batched
// col-flush (shfl + colpart LDS + sync + 128 atomics). 34KB LDS -> 4 blocks/CU.
// XCD swizzle bijective (2080 = 8*260).
__global__ __launch_bounds__(256) void kmain(const unsigned short* __restrict__ reps,
                                             float* __restrict__ rowsum) {
    __shared__ __align__(16) char ldsB[64 * 512];   // 32 KiB
    __shared__ float colpart[4][128];               // 2 KiB

    const int tid = threadIdx.x;
    const int wave = tid >> 6, lane = tid & 63;
    const int l15 = lane & 15, lhi = lane >> 4;

    // bijective XCD swizzle + tile decode
    int t = (blockIdx.x & 7) * 260 + (blockIdx.x >> 3);
    int rt, s;
    if (t < 1056) { rt = t / 33; s = t - rt * 33; }
    else          { int u = t - 1056; rt = 32 + (u >> 5); s = u & 31; }
    const int ct = (rt + s) & 63;
    const bool do_col = (s > 0);

    const int rowbaseW = rt * 128 + wave * 32;
    const char* repsb = (const char*)reps;

    // A fragments: 2 row-frags x 8 k-steps, 16B each  (R10 verbatim)
    short8 afrag[2][8];
#pragma unroll
    for (int rf = 0; rf < 2; ++rf) {
        const char* arow = repsb + (size_t)(rowbaseW + rf * 16 + l15) * ROWB;
#pragma unroll
        for (int ks = 0; ks < 8; ++ks)
            afrag[rf][ks] = *(const short8*)(arow + ks * 64 + lhi * 16);
    }

    float rsum[2][4];
#pragma unroll
    for (int rf = 0; rf < 2; ++rf)
#pragma unroll
        for (int r = 0; r < 4; ++r) rsum[rf][r] = 0.0f;

    float colsum[2][4];

#pragma unroll
    for (int sub = 0; sub < 2; ++sub) {
        const int colbase = ct * 128 + sub * 64;

        // stage B tile [64 cols][512 B] with slot XOR-swizzle  (R10 verbatim)
#pragma unroll
        for (int i = 0; i < 8; ++i) {
            int o = tid * 16 + i * 4096;
            int row = o >> 9;
            int slot = (o >> 4) & 31;
            uint4 v = *(const uint4*)(repsb + (size_t)(colbase + row) * ROWB + slot * 16);
            int dslot = slot ^ (row & 7);
            *(uint4*)(ldsB + row * 512 + dslot * 16) = v;
        }
        __syncthreads();

        f32x4 acc[2][4];
#pragma unroll
        for (int rf = 0; rf < 2; ++rf)
#pragma unroll
            for (int cf = 0; cf < 4; ++cf) acc[rf][cf] = (f32x4){0.f, 0.f, 0.f, 0.f};

#pragma unroll
        for (int ks = 0; ks < 8; ++ks) {
            short8 bfr[4];
#pragma unroll
            for (int cf = 0; cf < 4; ++cf) {
                int col = cf * 16 + l15;
                int slot = ks * 4 + lhi;
                int ds = slot ^ (col & 7);
                bfr[cf] = *(const short8*)(ldsB + col * 512 + ds * 16);
            }
#pragma unroll
            for (int rf = 0; rf < 2; ++rf)
#pragma unroll
                for (int cf = 0; cf < 4; ++cf)
                    acc[rf][cf] = __builtin_amdgcn_mfma_f32_16x16x32_bf16(
                        afrag[rf][ks], bfr[cf], acc[rf][cf], 0, 0, 0);
        }
        __syncthreads();

        // epilogue: exp once, feed row-partials (regs) + col-partials (regs)
#pragma unroll
        for (int cf = 0; cf < 4; ++cf) {
            float cacc = 0.0f;
#pragma unroll
            for (int rf = 0; rf < 2; ++rf) {
                f32x4 cv = acc[rf][cf];
#pragma unroll
                for (int r = 0; r < 4; ++r) {
                    float e = __builtin_amdgcn_exp2f(cv[r] * C_EXP);
                    rsum[rf][r] += e;
                    cacc += e;
                }
            }
            colsum[sub][cf] = cacc;
        }
    }

    // batched col-flush (symmetry), once per tile
    if (do_col) {   // block-uniform
#pragma unroll
        for (int sub = 0; sub < 2; ++sub)
#pragma unroll
            for (int cf = 0; cf < 4; ++cf) {
                float v = colsum[sub][cf];
                v += __shfl_xor(v, 16, 64);
                v += __shfl_xor(v, 32, 64);
                if (lane < 16) colpart[wave][sub * 64 + cf * 16 + lane] = v;
            }
        __syncthreads();
        if (tid < 128)
            atomicAdd(&rowsum[ct * 128 + tid],
                      colpart[0][tid] + colpart[1][tid] +
                      colpart[2][tid] + colpart[3][tid]);
    }

    // row-partials: reduce 16 lanes sharing each row, one atomic per row  (R10 verbatim)
#pragma unroll
    for (int rf = 0; rf < 2; ++rf)
#pragma unroll
        for (int r = 0; r < 4; ++r) {
            float v = rsum[rf][r];
            v += __shfl_xor(v, 1, 64);
            v += __shfl_xor(v, 2, 64);
            v += __shfl_xor(v, 4, 64);
            v += __shfl_xor(v, 8, 64);
            if (l15 == 0)
                atomicAdd(&rowsum[rowbaseW + rf * 16 + lhi * 4 + r], v);
        }
}

// ---------- K3: loss = mean(log(rowsum - selfexp) - pos) ----------
__global__ __launch_bounds__(1024) void kfinal(const float* __restrict__ rowsum,
                                               const float* __restrict__ pos,
                                               const float* __restrict__ selfexp,
                                               float* __restrict__ out) {
    __shared__ float red[16];
    float local = 0.0f;
    for (int r = threadIdx.x; r < TWO_N; r += 1024)
        local += __builtin_amdgcn_logf(rowsum[r] - selfexp[r]) * 0.6931471805599453f - pos[r];
#pragma unroll
    for (int m = 1; m < 64; m <<= 1) local += __shfl_xor(local, m, 64);
    if ((threadIdx.x & 63) == 0) red[threadIdx.x >> 6] = local;
    __syncthreads();
    if (threadIdx.x == 0) {
        float t = 0.0f;
#pragma unroll
        for (int i = 0; i < 16; ++i) t += red[i];
        out[0] = t * (1.0f / (float)TWO_N);
    }
}

extern "C" void kernel_launch(void* const* d_in, const int* in_sizes, int n_in,
                              void* d_out, int out_size, void* d_ws, size_t ws_size,
                              hipStream_t stream) {
    const float* zi = (const float*)d_in[0];
    const float* zj = (const float*)d_in[1];
    float* out = (float*)d_out;

    unsigned short* reps = (unsigned short*)d_ws;                       // 4 MiB
    float* rowsum = (float*)((char*)d_ws + (size_t)TWO_N * D_DIM * 2);  // 32 KiB
    float* pos = rowsum + TWO_N;                                        // 32 KiB
    float* selfexp = pos + TWO_N;                                       // 32 KiB

    kprep<<<1024, 256, 0, stream>>>(zi, zj, reps, pos, selfexp, rowsum);
    kmain<<<2080, 256, 0, stream>>>(reps, rowsum);
    kfinal<<<1, 1024, 0, stream>>>(rowsum, pos, selfexp, out);
}

// Round 13
// 53.666 us; speedup vs baseline: 1.1094x; 1.1094x over previous
//
#include <hip/hip_runtime.h>
#include <hip/hip_bf16.h>
#include <stdint.h>

#define N_ROWS 4096
#define D_DIM  256
#define TWO_N  8192
#define ROWB   512                       // bytes per bf16 row
#define C_EXP  2.8853900817779268f       // 2*log2(e): exp(2*dot)=2^(dot*2*log2e)

typedef __attribute__((ext_vector_type(8))) short short8;
typedef __attribute__((ext_vector_type(4))) float f32x4;

__device__ __forceinline__ unsigned bf16rne(float f) {
    unsigned u = __float_as_uint(f);
    return (u + 0x7fffu + ((u >> 16) & 1u)) >> 16;
}
__device__ __forceinline__ float bf16val(unsigned bits) {
    return __uint_as_float(bits << 16);
}

// ---------- K1: normalize -> bf16 reps, exact pos-pair sims, bf16 self-dot exp, zero rowsum ----------
__global__ __launch_bounds__(256) void kprep(const float* __restrict__ zi,
                                             const float* __restrict__ zj,
                                             unsigned short* __restrict__ reps,
                                             float* __restrict__ pos,
                                             float* __restrict__ selfexp,
                                             float* __restrict__ rowsum) {
    int wave = threadIdx.x >> 6, lane = threadIdx.x & 63;
    int k = blockIdx.x * 4 + wave;   // 0..4095
    float4 a = *(const float4*)(zi + (size_t)k * D_DIM + lane * 4);
    float4 b = *(const float4*)(zj + (size_t)k * D_DIM + lane * 4);
    float dii = a.x * a.x + a.y * a.y + a.z * a.z + a.w * a.w;
    float djj = b.x * b.x + b.y * b.y + b.z * b.z + b.w * b.w;
    float dij = a.x * b.x + a.y * b.y + a.z * b.z + a.w * b.w;
#pragma unroll
    for (int m = 1; m < 64; m <<= 1) {
        dii += __shfl_xor(dii, m, 64);
        djj += __shfl_xor(djj, m, 64);
        dij += __shfl_xor(dij, m, 64);
    }
    float si = 1.0f / fmaxf(sqrtf(dii), 1e-12f);
    float sj = 1.0f / fmaxf(sqrtf(djj), 1e-12f);

    unsigned a0 = bf16rne(a.x * si), a1 = bf16rne(a.y * si);
    unsigned a2 = bf16rne(a.z * si), a3 = bf16rne(a.w * si);
    unsigned b0 = bf16rne(b.x * sj), b1 = bf16rne(b.y * sj);
    unsigned b2 = bf16rne(b.z * sj), b3 = bf16rne(b.w * sj);
    {
        uint2 o; o.x = a0 | (a1 << 16); o.y = a2 | (a3 << 16);
        *(uint2*)(reps + (size_t)k * D_DIM + lane * 4) = o;
    }
    {
        uint2 o; o.x = b0 | (b1 << 16); o.y = b2 | (b3 << 16);
        *(uint2*)(reps + (size_t)(k + N_ROWS) * D_DIM + lane * 4) = o;
    }
    float fa0 = bf16val(a0), fa1 = bf16val(a1), fa2 = bf16val(a2), fa3 = bf16val(a3);
    float fb0 = bf16val(b0), fb1 = bf16val(b1), fb2 = bf16val(b2), fb3 = bf16val(b3);
    float sa = fa0 * fa0 + fa1 * fa1 + fa2 * fa2 + fa3 * fa3;
    float sb = fb0 * fb0 + fb1 * fb1 + fb2 * fb2 + fb3 * fb3;
#pragma unroll
    for (int m = 1; m < 64; m <<= 1) {
        sa += __shfl_xor(sa, m, 64);
        sb += __shfl_xor(sb, m, 64);
    }
    if (lane == 0) {
        float p = dij * si * sj * 2.0f;   // /TEMPERATURE
        pos[k] = p;
        pos[k + N_ROWS] = p;
        selfexp[k] = __builtin_amdgcn_exp2f(sa * C_EXP);
        selfexp[k + N_ROWS] = __builtin_amdgcn_exp2f(sb * C_EXP);
    }
    if (threadIdx.x < 8) rowsum[blockIdx.x * 8 + threadIdx.x] = 0.0f;
}

// ---------- K2: wrap symmetry, 2 tiles (4 sub-tiles) per block, batched flush ----------
// 1056 blocks: b<1024 -> rt=b>>4, s in {2p, 2p+1} (p=b&15); b>=1024 -> rt=b-1024, s=32.
// Tile (rt,s): ct=(rt+s)&63. Coverage (validated R11/R12): each ordered pair exactly
// once — direct for s in 0..32, mirrors via col-emission. s=0 emits rows only.
// A-frags loaded ONCE per block (same rt). Inner loop per sub-tile: R10 verbatim.
// Colsums kept in regs across the block; ONE batched flush at end (1 extra barrier,
// 256 col atomics + 128 row atomics). LDS 36KB -> 4 blocks/CU; VGPR target <=125.
// Bijective XCD swizzle (1056 = 8*132).
__global__ __launch_bounds__(256) void kmain(const unsigned short* __restrict__ reps,
                                             float* __restrict__ rowsum) {
    __shared__ __align__(16) char ldsB[64 * 512];   // 32 KiB
    __shared__ float colpart[4][256];               // 4 KiB

    const int tid = threadIdx.x;
    const int wave = tid >> 6, lane = tid & 63;
    const int l15 = lane & 15, lhi = lane >> 4;

    // bijective XCD swizzle + block decode
    int b = (blockIdx.x & 7) * 132 + (blockIdx.x >> 3);
    int rt, s0, nt;
    if (b < 1024) { rt = b >> 4; s0 = (b & 15) * 2; nt = 2; }
    else          { rt = b - 1024; s0 = 32; nt = 1; }

    const int rowbaseW = rt * 128 + wave * 32;
    const char* repsb = (const char*)reps;

    // A fragments: 2 row-frags x 8 k-steps, once per block  (R10 verbatim)
    short8 afrag[2][8];
#pragma unroll
    for (int rf = 0; rf < 2; ++rf) {
        const char* arow = repsb + (size_t)(rowbaseW + rf * 16 + l15) * ROWB;
#pragma unroll
        for (int ks = 0; ks < 8; ++ks)
            afrag[rf][ks] = *(const short8*)(arow + ks * 64 + lhi * 16);
    }

    float rsum[2][4];
#pragma unroll
    for (int rf = 0; rf < 2; ++rf)
#pragma unroll
        for (int r = 0; r < 4; ++r) rsum[rf][r] = 0.0f;

    float colsum[2][2][4];   // [tile][sub][cf]

    for (int ti = 0; ti < nt; ++ti) {
        const int ct = (rt + s0 + ti) & 63;

#pragma unroll
        for (int sub = 0; sub < 2; ++sub) {
            const int colbase = ct * 128 + sub * 64;

            // stage B tile [64 cols][512 B] with slot XOR-swizzle  (R10 verbatim)
#pragma unroll
            for (int i = 0; i < 8; ++i) {
                int o = tid * 16 + i * 4096;
                int row = o >> 9;
                int slot = (o >> 4) & 31;
                uint4 v = *(const uint4*)(repsb + (size_t)(colbase + row) * ROWB + slot * 16);
                int dslot = slot ^ (row & 7);
                *(uint4*)(ldsB + row * 512 + dslot * 16) = v;
            }
            __syncthreads();

            f32x4 acc[2][4];
#pragma unroll
            for (int rf = 0; rf < 2; ++rf)
#pragma unroll
                for (int cf = 0; cf < 4; ++cf) acc[rf][cf] = (f32x4){0.f, 0.f, 0.f, 0.f};

#pragma unroll
            for (int ks = 0; ks < 8; ++ks) {
                short8 bfr[4];
#pragma unroll
                for (int cf = 0; cf < 4; ++cf) {
                    int col = cf * 16 + l15;
                    int slot = ks * 4 + lhi;
                    int ds = slot ^ (col & 7);
                    bfr[cf] = *(const short8*)(ldsB + col * 512 + ds * 16);
                }
#pragma unroll
                for (int rf = 0; rf < 2; ++rf)
#pragma unroll
                    for (int cf = 0; cf < 4; ++cf)
                        acc[rf][cf] = __builtin_amdgcn_mfma_f32_16x16x32_bf16(
                            afrag[rf][ks], bfr[cf], acc[rf][cf], 0, 0, 0);
            }
            __syncthreads();

            // epilogue: exp once, feed row-partials (regs) + col-partials (regs)
#pragma unroll
            for (int cf = 0; cf < 4; ++cf) {
                float cacc = 0.0f;
#pragma unroll
                for (int rf = 0; rf < 2; ++rf) {
                    f32x4 cv = acc[rf][cf];
#pragma unroll
                    for (int r = 0; r < 4; ++r) {
                        float e = __builtin_amdgcn_exp2f(cv[r] * C_EXP);
                        rsum[rf][r] += e;
                        cacc += e;
                    }
                }
                colsum[ti][sub][cf] = cacc;
            }
        }
    }

    // batched col-flush: reduce in-wave, stash to LDS, one sync, one atomic/col
    for (int ti = 0; ti < nt; ++ti)
#pragma unroll
        for (int sub = 0; sub < 2; ++sub)
#pragma unroll
            for (int cf = 0; cf < 4; ++cf) {
                float v = colsum[ti][sub][cf];
                v += __shfl_xor(v, 16, 64);
                v += __shfl_xor(v, 32, 64);
                if (lane < 16)
                    colpart[wave][ti * 128 + sub * 64 + cf * 16 + lane] = v;
            }
    __syncthreads();
    {
        int ti = tid >> 7;                 // 0..1
        int c  = tid & 127;
        int s  = s0 + ti;
        if (ti < nt && s > 0) {            // s==0 tile emits rows only
            int ct = (rt + s) & 63;
            atomicAdd(&rowsum[ct * 128 + c],
                      colpart[0][tid] + colpart[1][tid] +
                      colpart[2][tid] + colpart[3][tid]);
        }
    }

    // row-partials: reduce 16 lanes sharing each row, one atomic per row  (R10 verbatim)
#pragma unroll
    for (int rf = 0; rf < 2; ++rf)
#pragma unroll
        for (int r = 0; r < 4; ++r) {
            float v = rsum[rf][r];
            v += __shfl_xor(v, 1, 64);
            v += __shfl_xor(v, 2, 64);
            v += __shfl_xor(v, 4, 64);
            v += __shfl_xor(v, 8, 64);
            if (l15 == 0)
                atomicAdd(&rowsum[rowbaseW + rf * 16 + lhi * 4 + r], v);
        }
}

// ---------- K3: loss = mean(log(rowsum - selfexp) - pos) ----------
__global__ __launch_bounds__(1024) void kfinal(const float* __restrict__ rowsum,
                                               const float* __restrict__ pos,
                                               const float* __restrict__ selfexp,
                                               float* __restrict__ out) {
    __shared__ float red[16];
    float local = 0.0f;
    for (int r = threadIdx.x; r < TWO_N; r += 1024)
        local += __builtin_amdgcn_logf(rowsum[r] - selfexp[r]) * 0.6931471805599453f - pos[r];
#pragma unroll
    for (int m = 1; m < 64; m <<= 1) local += __shfl_xor(local, m, 64);
    if ((threadIdx.x & 63) == 0) red[threadIdx.x >> 6] = local;
    __syncthreads();
    if (threadIdx.x == 0) {
        float t = 0.0f;
#pragma unroll
        for (int i = 0; i < 16; ++i) t += red[i];
        out[0] = t * (1.0f / (float)TWO_N);
    }
}

extern "C" void kernel_launch(void* const* d_in, const int* in_sizes, int n_in,
                              void* d_out, int out_size, void* d_ws, size_t ws_size,
                              hipStream_t stream) {
    const float* zi = (const float*)d_in[0];
    const float* zj = (const float*)d_in[1];
    float* out = (float*)d_out;

    unsigned short* reps = (unsigned short*)d_ws;                       // 4 MiB
    float* rowsum = (float*)((char*)d_ws + (size_t)TWO_N * D_DIM * 2);  // 32 KiB
    float* pos = rowsum + TWO_N;                                        // 32 KiB
    float* selfexp = pos + TWO_N;                                       // 32 KiB

    kprep<<<1024, 256, 0, stream>>>(zi, zj, reps, pos, selfexp, rowsum);
    kmain<<<1056, 256, 0, stream>>>(reps, rowsum);
    kfinal<<<1, 1024, 0, stream>>>(rowsum, pos, selfexp, out);
}